// Round 1
// 143.555 us; speedup vs baseline: 1.0747x; 1.0747x over previous
//
#include <hip/hip_runtime.h>
#include <math.h>

#define NN 256
#define NS 512
#define MS 32
#define NSTEP 32
#define VRESET 1.0f

__device__ __forceinline__ float sigf(float x) {
    // fast sigmoid: v_exp_f32 + v_rcp_f32 (~3 ulp); verified no event flips
    // (absmax identical to OCML expf version: 0.125).
    float e = __expf(-x);
    return __builtin_amdgcn_rcpf(1.0f + e);
}

// Barrier WITHOUT the vmcnt(0) drain that __syncthreads() emits.
// Cross-wave communication here is LDS-only, so lgkmcnt(0) + s_barrier is
// sufficient; global stores (round outputs) and loads (reset_s prefetch)
// deliberately stay in flight across it. Memory clobbers pin ordering of the
// ds ops around the barrier (guide §5/§6: hipcc's __syncthreads drains vmcnt).
__device__ __forceinline__ void block_sync_lds() {
    asm volatile("s_waitcnt lgkmcnt(0)" ::: "memory");
    __builtin_amdgcn_s_barrier();
    asm volatile("" ::: "memory");
}

// One RK4 step — op-for-op identical order to the previous (verified) kernel.
__device__ __forceinline__ void rk4step(float v, float ii, float s,
                                        float ic, float mu1, float mu2,
                                        float dt, float hh, float h6,
                                        float& vn, float& in_, float& sn)
{
    float kv1 = mu1 * (ii + ic - v);
    float ki1 = -mu2 * ii;
    float ks1 = sigf(v);
    float v2 = v + hh * kv1;
    float i2 = ii + hh * ki1;
    float kv2 = mu1 * (i2 + ic - v2);
    float ki2 = -mu2 * i2;
    float ks2 = sigf(v2);
    float v3 = v + hh * kv2;
    float i3 = ii + hh * ki2;
    float kv3 = mu1 * (i3 + ic - v3);
    float ki3 = -mu2 * i3;
    float ks3 = sigf(v3);
    float v4 = v + dt * kv3;
    float i4 = ii + dt * ki3;
    float kv4 = mu1 * (i4 + ic - v4);
    float ki4 = -mu2 * i4;
    float ks4 = sigf(v4);
    vn  = v  + h6 * (kv1 + 2.0f * kv2 + 2.0f * kv3 + kv4);
    in_ = ii + h6 * (ki1 + 2.0f * ki2 + 2.0f * ki3 + ki4);
    sn  = s  + h6 * (ks1 + 2.0f * ks2 + 2.0f * ks3 + ks4);
}

// One block (256 threads = 4 waves) per sample; thread tid owns neuron tid.
// Changes vs previous version (all value-identical):
//  - crossing check pipelined one step: flag write at iteration top,
//    speculative RK4 of step st+1 overlaps the barrier, flag read after.
//    4-slot flag rotation (st&3) gives the required >2-step WAR separation
//    with one barrier per step.
//  - reset_s row prefetched unconditionally at round start (latency hidden
//    under step loop + event processing; +16 MB fetch, BW is 12% utilized).
//  - event processing: single barrier; u64 packed argmax key
//    (ordered(sn)<<32 | (255-tid): value desc, index asc — same tiebreak),
//    eidx ballot fused into the same LDS round, s_prev/sn of the winner
//    fetched from LDS scatter; w[eidx] row load issued before interp math.
__global__ __launch_bounds__(256) void snn_kernel(
    const float* __restrict__ ic_g,     // (256,)
    const float* __restrict__ w,        // (256,256)
    const float* __restrict__ mu,       // (2,)
    const float* __restrict__ v0,       // (256,)
    const float* __restrict__ i0,       // (256,)
    const float* __restrict__ s0,       // (512,256)
    const float* __restrict__ reset_s,  // (32,512,256)
    const int*   __restrict__ t1p,      // scalar
    float* __restrict__ out)
{
    const int tid  = threadIdx.x;   // neuron index
    const int lane = tid & 63;
    const int wid  = tid >> 6;
    const int samp = blockIdx.x;
    const float mu1 = mu[0];
    const float mu2 = mu[1];
    const float t1f = (float)t1p[0];

    __shared__ int   s_any[4][4];                 // flag slots, st&3 rotation
    __shared__ float s_sn[NN];                    // sn at event
    __shared__ float s_sp[NN];                    // s_prev at event
    __shared__ unsigned long long s_key[4];       // per-wave argmax key
    __shared__ int   s_eidx[4];                   // per-wave min crossed idx

    float v  = v0[tid];
    float ii = i0[tid];
    float s  = s0[samp * NN + tid];
    const float ic = ic_g[tid];
    float t0 = 0.0f;

    float* times = out;                                  // [NS][MS]
    float* vals  = out + (size_t)NS * MS;                // [NS][MS][NN][3]
    float* marks = out + (size_t)NS * MS * (1 + NN * 3); // [NS][MS][NN]

    for (int r = 0; r < MS; ++r) {
        // Prefetch this round's reset row NOW (coalesced 1 KB/block).
        // Consumed only in the reset path; raw barriers keep it in flight.
        const float rs = reset_s[((size_t)r * NS + samp) * NN + tid];

        const float dt = (t1f - t0) / (float)NSTEP;
        float tev = t1f;
        float yv = v, yi = ii, ys = s;
        bool  em = false;
        bool  done = false;
        float wr = 0.0f;

        if (dt != 0.0f) {
            const float hh = 0.5f * dt;
            const float h6 = dt * (1.0f / 6.0f);

            // prologue: y1 = RK4(y0)
            float pv = v, pi_ = ii, ps = s;      // y_st
            float cv, ci, cs;                    // y_{st+1}
            rk4step(pv, pi_, ps, ic, mu1, mu2, dt, hh, h6, cv, ci, cs);
            float t = t0;

            for (int st = 0; st < NSTEP; ++st) {
                // 1) publish flag for step st immediately (max barrier overlap)
                unsigned long long bl = __ballot(cs > 0.0f);
                if (lane == 0) s_any[st & 3][wid] = (bl != 0ull) ? 1 : 0;

                // 2) speculative step st+1 while other waves reach the barrier
                float nv = 0.0f, ni = 0.0f, ns_ = 0.0f;
                const bool notlast = (st + 1 < NSTEP);
                if (notlast)
                    rk4step(cv, ci, cs, ic, mu1, mu2, dt, hh, h6, nv, ni, ns_);

                // 3) rendezvous + read flag of step st
                block_sync_lds();
                int af = s_any[st & 3][0] | s_any[st & 3][1] |
                         s_any[st & 3][2] | s_any[st & 3][3];

                if (af) {
                    // ---- event at step st: interpolate y_st <-> y_{st+1} ----
                    bool crossed = cs > 0.0f;
                    s_sn[tid] = cs;
                    s_sp[tid] = ps;

                    // packed argmax key: value desc, index asc on ties
                    unsigned int b = __float_as_uint(cs);
                    unsigned int m = (b & 0x80000000u) ? 0xFFFFFFFFu : 0x80000000u;
                    unsigned long long key =
                        ((unsigned long long)(b ^ m) << 32) |
                        (unsigned int)(NN - 1 - tid);
#pragma unroll
                    for (int off = 32; off >= 1; off >>= 1) {
                        unsigned long long o = __shfl_xor(key, off);
                        key = (o > key) ? o : key;
                    }
                    // fused per-wave min crossed index
                    unsigned long long bm = __ballot(crossed);
                    int cand = (bm != 0ull)
                                   ? (wid * 64 + (int)__builtin_ctzll(bm))
                                   : (2 * NN);
                    if (lane == 0) { s_key[wid] = key; s_eidx[wid] = cand; }
                    block_sync_lds();

                    unsigned long long k0 = s_key[0], k1 = s_key[1];
                    unsigned long long k2 = s_key[2], k3 = s_key[3];
                    k0 = (k1 > k0) ? k1 : k0;
                    k2 = (k3 > k2) ? k3 : k2;
                    k0 = (k2 > k0) ? k2 : k0;
                    int bn = NN - 1 - (int)(unsigned int)(k0 & 0xFFFFFFFFull);

                    int eidx = s_eidx[0];
                    eidx = (s_eidx[1] < eidx) ? s_eidx[1] : eidx;
                    eidx = (s_eidx[2] < eidx) ? s_eidx[2] : eidx;
                    eidx = (s_eidx[3] < eidx) ? s_eidx[3] : eidx;

                    // issue the w-row load early; L2 latency hides under interp
                    wr = w[eidx * NN + tid];

                    float bv  = s_sn[bn];
                    float bsp = s_sp[bn];
                    float frac = bsp / (bsp - bv + 1e-12f);
                    frac = fminf(fmaxf(frac, 0.0f), 1.0f);
                    tev = t + frac * dt;
                    yv = pv  + frac * (cv - pv);
                    yi = pi_ + frac * (ci - pi_);
                    ys = ps  + frac * (cs - ps);
                    em = crossed;
                    done = true;
                    break;
                }

                // 4) advance the pipeline
                if (notlast) {
                    pv = cv; pi_ = ci; ps = cs;
                    cv = nv; ci = ni; cs = ns_;
                    t += dt;
                }
            }

            if (!done) { yv = cv; yi = ci; ys = cs; }  // full 32 steps, no event
        }

        // ---- emit round outputs (stores stay in flight across barriers) ----
        const int sr = samp * MS + r;
        if (tid == 0) times[sr] = tev;
        {
            float* p = vals + ((size_t)sr * NN + tid) * 3;
            p[0] = yv;
            p[1] = yi;
            p[2] = ys;
            marks[(size_t)sr * NN + tid] = em ? 1.0f : 0.0f;
        }

        // ---- reset for next round ----
        if (done) {
            v  = yv - (em ? VRESET : 0.0f);
            ii = yi + wr;
            float sres = em ? rs : ys;
            s = fminf(sres, 0.0f);
        } else {
            v = yv; ii = yi;
            s = fminf(ys, 0.0f);
        }
        t0 = tev;
    }
}

extern "C" void kernel_launch(void* const* d_in, const int* in_sizes, int n_in,
                              void* d_out, int out_size, void* d_ws, size_t ws_size,
                              hipStream_t stream) {
    const float* ic      = (const float*)d_in[0];
    const float* w       = (const float*)d_in[1];
    const float* mu      = (const float*)d_in[2];
    const float* v0      = (const float*)d_in[3];
    const float* i0      = (const float*)d_in[4];
    const float* s0      = (const float*)d_in[5];
    const float* reset_s = (const float*)d_in[6];
    const int*   t1p     = (const int*)d_in[7];
    float* out = (float*)d_out;

    snn_kernel<<<dim3(NS), dim3(256), 0, stream>>>(ic, w, mu, v0, i0, s0,
                                                   reset_s, t1p, out);
}

// Round 2
// 135.867 us; speedup vs baseline: 1.1355x; 1.0566x over previous
//
#include <hip/hip_runtime.h>
#include <math.h>

#define NN 256
#define NS 512
#define MS 32
#define NSTEP 32
#define VRESET 1.0f

__device__ __forceinline__ float sigf(float x) {
    // fast sigmoid: v_exp_f32 + v_rcp_f32 (~3 ulp); verified no event flips
    // (absmax identical to OCML expf version: 0.125).
    float e = __expf(-x);
    return __builtin_amdgcn_rcpf(1.0f + e);
}

// Barrier WITHOUT the vmcnt(0) drain that __syncthreads() emits.
// Cross-wave communication here is LDS-only, so lgkmcnt(0) + s_barrier is
// sufficient; global stores (round outputs) and loads (reset_s prefetch)
// deliberately stay in flight across it.
__device__ __forceinline__ void block_sync_lds() {
    asm volatile("s_waitcnt lgkmcnt(0)" ::: "memory");
    __builtin_amdgcn_s_barrier();
    asm volatile("" ::: "memory");
}

// Full RK4 step — op-for-op identical order to the verified kernel.
// Used in the prologue only; the in-loop copy is split around the barrier.
__device__ __forceinline__ void rk4step(float v, float ii, float s,
                                        float ic, float mu1, float mu2,
                                        float dt, float hh, float h6,
                                        float& vn, float& in_, float& sn)
{
    float kv1 = mu1 * (ii + ic - v);
    float ki1 = -mu2 * ii;
    float ks1 = sigf(v);
    float v2 = v + hh * kv1;
    float i2 = ii + hh * ki1;
    float kv2 = mu1 * (i2 + ic - v2);
    float ki2 = -mu2 * i2;
    float ks2 = sigf(v2);
    float v3 = v + hh * kv2;
    float i3 = ii + hh * ki2;
    float kv3 = mu1 * (i3 + ic - v3);
    float ki3 = -mu2 * i3;
    float ks3 = sigf(v3);
    float v4 = v + dt * kv3;
    float i4 = ii + dt * ki3;
    float kv4 = mu1 * (i4 + ic - v4);
    float ki4 = -mu2 * i4;
    float ks4 = sigf(v4);
    vn  = v  + h6 * (kv1 + 2.0f * kv2 + 2.0f * kv3 + kv4);
    in_ = ii + h6 * (ki1 + 2.0f * ki2 + 2.0f * ki3 + ki4);
    sn  = s  + h6 * (ks1 + 2.0f * ks2 + 2.0f * ks3 + ks4);
}

// One block (256 threads = 4 waves) per sample; thread tid owns neuron tid.
// R2 change (value-identical): the speculative RK4 of step st+1 is SPLIT
// around the barrier — k1/k2 before (covers the flag ds_write drain), k3/k4
// after, between the int4 flag-read issue and its use (covers the ds_read
// latency). Flags are packed in an int4 so the post-barrier read is a single
// ds_read_b128. sched_barrier(0) pins the halves (hipcc otherwise floats
// register-only FP ops across asm with memory clobbers).
__global__ __launch_bounds__(256) void snn_kernel(
    const float* __restrict__ ic_g,     // (256,)
    const float* __restrict__ w,        // (256,256)
    const float* __restrict__ mu,       // (2,)
    const float* __restrict__ v0,       // (256,)
    const float* __restrict__ i0,       // (256,)
    const float* __restrict__ s0,       // (512,256)
    const float* __restrict__ reset_s,  // (32,512,256)
    const int*   __restrict__ t1p,      // scalar
    float* __restrict__ out)
{
    const int tid  = threadIdx.x;   // neuron index
    const int lane = tid & 63;
    const int wid  = tid >> 6;
    const int samp = blockIdx.x;
    const float mu1 = mu[0];
    const float mu2 = mu[1];
    const float t1f = (float)t1p[0];

    __shared__ int4  s_any4[4];                   // packed flags, st&3 rotation
    __shared__ float s_sn[NN];                    // sn at event
    __shared__ float s_sp[NN];                    // s_prev at event
    __shared__ unsigned long long s_key[4];       // per-wave argmax key
    __shared__ int   s_eidx[4];                   // per-wave min crossed idx

    float v  = v0[tid];
    float ii = i0[tid];
    float s  = s0[samp * NN + tid];
    const float ic = ic_g[tid];
    float t0 = 0.0f;

    float* times = out;                                  // [NS][MS]
    float* vals  = out + (size_t)NS * MS;                // [NS][MS][NN][3]
    float* marks = out + (size_t)NS * MS * (1 + NN * 3); // [NS][MS][NN]

    for (int r = 0; r < MS; ++r) {
        // Prefetch this round's reset row NOW (coalesced 1 KB/block).
        // Consumed only in the reset path; raw barriers keep it in flight.
        const float rs = reset_s[((size_t)r * NS + samp) * NN + tid];

        const float dt = (t1f - t0) / (float)NSTEP;
        float tev = t1f;
        float yv = v, yi = ii, ys = s;
        bool  em = false;
        bool  done = false;
        float wr = 0.0f;

        if (dt != 0.0f) {
            const float hh = 0.5f * dt;
            const float h6 = dt * (1.0f / 6.0f);

            // prologue: c = y_1 = RK4(y_0)
            float pv = v, pi_ = ii, ps = s;      // y_st
            float cv, ci, cs;                    // y_{st+1}
            rk4step(pv, pi_, ps, ic, mu1, mu2, dt, hh, h6, cv, ci, cs);
            float t = t0;

            for (int st = 0; st < NSTEP; ++st) {
                // 1) publish flag(st) = any(y_{st+1}.s > 0)
                unsigned long long bl = __ballot(cs > 0.0f);
                if (lane == 0)
                    ((int*)&s_any4[st & 3])[wid] = (bl != 0ull) ? 1 : 0;

                // 2a) speculative y_{st+2}, first half (k1,k2) — covers the
                //     flag ds_write drain inside block_sync_lds
                float kv1 = mu1 * (ci + ic - cv);
                float ki1 = -mu2 * ci;
                float ks1 = sigf(cv);
                float v2 = cv + hh * kv1;
                float i2 = ci + hh * ki1;
                float kv2 = mu1 * (i2 + ic - v2);
                float ki2 = -mu2 * i2;
                float ks2 = sigf(v2);

                __builtin_amdgcn_sched_barrier(0);
                // 3) rendezvous
                block_sync_lds();
                __builtin_amdgcn_sched_barrier(0);

                // 4) issue the packed flag read (one ds_read_b128)...
                int4 f = s_any4[st & 3];

                // 2b) ...and overlap its latency with the second half (k3,k4)
                float v3 = cv + hh * kv2;
                float i3 = ci + hh * ki2;
                float kv3 = mu1 * (i3 + ic - v3);
                float ki3 = -mu2 * i3;
                float ks3 = sigf(v3);
                float v4 = cv + dt * kv3;
                float i4 = ci + dt * ki3;
                float kv4 = mu1 * (i4 + ic - v4);
                float ki4 = -mu2 * i4;
                float ks4 = sigf(v4);
                float nv  = cv + h6 * (kv1 + 2.0f * kv2 + 2.0f * kv3 + kv4);
                float ni  = ci + h6 * (ki1 + 2.0f * ki2 + 2.0f * ki3 + ki4);
                float ns_ = cs + h6 * (ks1 + 2.0f * ks2 + 2.0f * ks3 + ks4);

                int af = f.x | f.y | f.z | f.w;

                if (af) {
                    // ---- event at step st: interpolate y_st <-> y_{st+1} ----
                    bool crossed = cs > 0.0f;
                    s_sn[tid] = cs;
                    s_sp[tid] = ps;

                    // packed argmax key: value desc, index asc on ties
                    unsigned int b = __float_as_uint(cs);
                    unsigned int m = (b & 0x80000000u) ? 0xFFFFFFFFu : 0x80000000u;
                    unsigned long long key =
                        ((unsigned long long)(b ^ m) << 32) |
                        (unsigned int)(NN - 1 - tid);
#pragma unroll
                    for (int off = 32; off >= 1; off >>= 1) {
                        unsigned long long o = __shfl_xor(key, off);
                        key = (o > key) ? o : key;
                    }
                    // fused per-wave min crossed index
                    unsigned long long bm = __ballot(crossed);
                    int cand = (bm != 0ull)
                                   ? (wid * 64 + (int)__builtin_ctzll(bm))
                                   : (2 * NN);
                    if (lane == 0) { s_key[wid] = key; s_eidx[wid] = cand; }
                    block_sync_lds();

                    unsigned long long k0 = s_key[0], k1 = s_key[1];
                    unsigned long long k2 = s_key[2], k3 = s_key[3];
                    k0 = (k1 > k0) ? k1 : k0;
                    k2 = (k3 > k2) ? k3 : k2;
                    k0 = (k2 > k0) ? k2 : k0;
                    int bn = NN - 1 - (int)(unsigned int)(k0 & 0xFFFFFFFFull);

                    int eidx = s_eidx[0];
                    eidx = (s_eidx[1] < eidx) ? s_eidx[1] : eidx;
                    eidx = (s_eidx[2] < eidx) ? s_eidx[2] : eidx;
                    eidx = (s_eidx[3] < eidx) ? s_eidx[3] : eidx;

                    // issue the w-row load early; L2 latency hides under interp
                    wr = w[eidx * NN + tid];

                    float bv  = s_sn[bn];
                    float bsp = s_sp[bn];
                    float frac = bsp / (bsp - bv + 1e-12f);
                    frac = fminf(fmaxf(frac, 0.0f), 1.0f);
                    tev = t + frac * dt;
                    yv = pv  + frac * (cv - pv);
                    yi = pi_ + frac * (ci - pi_);
                    ys = ps  + frac * (cs - ps);
                    em = crossed;
                    done = true;
                    break;
                }

                // 5) advance the pipeline
                pv = cv; pi_ = ci; ps = cs;
                cv = nv; ci = ni; cs = ns_;
                t += dt;
            }

            if (!done) { yv = cv; yi = ci; ys = cs; }  // full 32 steps, no event
        }

        // ---- emit round outputs (stores stay in flight across barriers) ----
        const int sr = samp * MS + r;
        if (tid == 0) times[sr] = tev;
        {
            float* p = vals + ((size_t)sr * NN + tid) * 3;
            p[0] = yv;
            p[1] = yi;
            p[2] = ys;
            marks[(size_t)sr * NN + tid] = em ? 1.0f : 0.0f;
        }

        // ---- reset for next round ----
        if (done) {
            v  = yv - (em ? VRESET : 0.0f);
            ii = yi + wr;
            float sres = em ? rs : ys;
            s = fminf(sres, 0.0f);
        } else {
            v = yv; ii = yi;
            s = fminf(ys, 0.0f);
        }
        t0 = tev;
    }
}

extern "C" void kernel_launch(void* const* d_in, const int* in_sizes, int n_in,
                              void* d_out, int out_size, void* d_ws, size_t ws_size,
                              hipStream_t stream) {
    const float* ic      = (const float*)d_in[0];
    const float* w       = (const float*)d_in[1];
    const float* mu      = (const float*)d_in[2];
    const float* v0      = (const float*)d_in[3];
    const float* i0      = (const float*)d_in[4];
    const float* s0      = (const float*)d_in[5];
    const float* reset_s = (const float*)d_in[6];
    const int*   t1p     = (const int*)d_in[7];
    float* out = (float*)d_out;

    snn_kernel<<<dim3(NS), dim3(256), 0, stream>>>(ic, w, mu, v0, i0, s0,
                                                   reset_s, t1p, out);
}